// Round 1
// baseline (2048.100 us; speedup 1.0000x reference)
//
#include <hip/hip_runtime.h>
#include <stdint.h>

#define B_BATCH 8
#define S_SEQ   4096
#define D_DIM   1024
#define H_DIM   2048
#define M_TOK   (B_BATCH * S_SEQ)   // 32768
#define MAXK    64

// ---------------- JAX threefry2x32 (20 rounds), partitionable mode ----------------

#define TF_ROUND(x0, x1, r) { x0 += x1; x1 = ((x1 << r) | (x1 >> (32 - r))); x1 ^= x0; }

__device__ __forceinline__ void tf2x32(uint32_t k0, uint32_t k1, uint32_t x0, uint32_t x1,
                                       uint32_t& o0, uint32_t& o1) {
  uint32_t k2 = k0 ^ k1 ^ 0x1BD11BDAu;
  x0 += k0; x1 += k1;
  TF_ROUND(x0, x1, 13) TF_ROUND(x0, x1, 15) TF_ROUND(x0, x1, 26) TF_ROUND(x0, x1, 6)
  x0 += k1; x1 += k2 + 1u;
  TF_ROUND(x0, x1, 17) TF_ROUND(x0, x1, 29) TF_ROUND(x0, x1, 16) TF_ROUND(x0, x1, 24)
  x0 += k2; x1 += k0 + 2u;
  TF_ROUND(x0, x1, 13) TF_ROUND(x0, x1, 15) TF_ROUND(x0, x1, 26) TF_ROUND(x0, x1, 6)
  x0 += k0; x1 += k1 + 3u;
  TF_ROUND(x0, x1, 17) TF_ROUND(x0, x1, 29) TF_ROUND(x0, x1, 16) TF_ROUND(x0, x1, 24)
  x0 += k1; x1 += k2 + 4u;
  TF_ROUND(x0, x1, 13) TF_ROUND(x0, x1, 15) TF_ROUND(x0, x1, 26) TF_ROUND(x0, x1, 6)
  x0 += k2; x1 += k0 + 5u;
  o0 = x0; o1 = x1;
}

// jax.random.key(42) -> key (0, 42); split (foldlike, partitionable=True):
// rng_j = (y0, y1) of threefry block with counter (0, j)
__device__ __forceinline__ void jax_subkeys(uint32_t& r1a, uint32_t& r1b,
                                            uint32_t& r2a, uint32_t& r2b) {
  tf2x32(0u, 42u, 0u, 0u, r1a, r1b);
  tf2x32(0u, 42u, 0u, 1u, r2a, r2b);
}

// partitionable 32-bit random bits for flat element i: y0 ^ y1 of block (0, i)
__device__ __forceinline__ uint32_t jax_bits32(uint32_t ka, uint32_t kb, uint32_t i) {
  uint32_t o0, o1;
  tf2x32(ka, kb, 0u, i, o0, o1);
  return o0 ^ o1;
}

// uniform(minval=1e-8, maxval=1-1e-8) in fp32: span rounds to exactly 1.0f
__device__ __forceinline__ float jax_uniform_from_bits(uint32_t bits) {
  float f = __uint_as_float((bits >> 9) | 0x3f800000u) - 1.0f;  // [0, 1)
  float r = f + 1e-8f;   // f * 1.0f (exact) + minval
  return fmaxf(1e-8f, r);
}

__device__ __forceinline__ float gumbel_from_bits(uint32_t bits) {
  float u = jax_uniform_from_bits(bits);
  return -logf(-logf(u));
}

// perturbed k-logit i (K_TAU == 1.0 so division is identity)
__device__ __forceinline__ float k_perturbed(int i, const float* kl) {
  uint32_t r1a, r1b, r2a, r2b;
  jax_subkeys(r1a, r1b, r2a, r2b);
  return kl[i] + gumbel_from_bits(jax_bits32(r1a, r1b, (uint32_t)i));
}

__device__ __forceinline__ uint32_t ordf(float v) {
  uint32_t b = __float_as_uint(v);
  return (b & 0x80000000u) ? ~b : (b | 0x80000000u);
}

__device__ __forceinline__ unsigned long long shflx64(unsigned long long v, int m) {
  unsigned lo = (unsigned)v, hi = (unsigned)(v >> 32);
  lo = (unsigned)__shfl_xor((int)lo, m);
  hi = (unsigned)__shfl_xor((int)hi, m);
  return ((unsigned long long)hi << 32) | lo;
}

// ---------------- K1: expected_k (single wave) ----------------

__global__ void kexp_kernel(const float* __restrict__ kl, float* __restrict__ expk) {
  int i = threadIdx.x;  // 0..63
  float p = k_perturbed(i, kl);
  float m = p;
  #pragma unroll
  for (int off = 32; off >= 1; off >>= 1) m = fmaxf(m, __shfl_xor(m, off));
  float e = expf(p - m);
  float s = e;
  #pragma unroll
  for (int off = 32; off >= 1; off >>= 1) s += __shfl_xor(s, off);
  float v = (e / s) * (float)(i + 1);
  #pragma unroll
  for (int off = 32; off >= 1; off >>= 1) v += __shfl_xor(v, off);
  if (i == 0) expk[0] = v;
}

// ---------------- K2: fused scorer GEMM -> perturbed logits ----------------
// BM=64 tokens/block, BN=128 (H tile, looped 16x), BK=16. 256 threads,
// thread tile 4 tokens x 8 h. Epilogue: relu(acc+b1)*W2 partial -> LDS reduce
// -> + b2 + token gumbel -> perturbed[t] (written into d_out mask region).

__global__ __launch_bounds__(256) void scorer_kernel(
    const float* __restrict__ emb, const float* __restrict__ W1,
    const float* __restrict__ b1, const float* __restrict__ W2,
    const float* __restrict__ b2, float* __restrict__ pert) {
  __shared__ float As[16][68];    // [k][token], stride 68 (16B-aligned rows, bank spread)
  __shared__ float Bs[16][132];   // [k][h]
  __shared__ float red[64][17];

  const int tid = threadIdx.x;
  const int tx = tid & 15;        // h group (8 each)
  const int ty = tid >> 4;        // token group (4 each)
  const int m0 = blockIdx.x * 64;

  const int at = tid >> 2;        // token 0..63 for A staging
  const int ac = (tid & 3) << 2;  // k offset 0/4/8/12
  const int br = tid >> 4;        // k row for B staging
  const int bc = (tid & 15) << 3; // h offset

  float logit[4] = {0.f, 0.f, 0.f, 0.f};

  for (int n0 = 0; n0 < H_DIM; n0 += 128) {
    float acc[4][8];
    #pragma unroll
    for (int i = 0; i < 4; i++)
      #pragma unroll
      for (int j = 0; j < 8; j++) acc[i][j] = 0.f;

    for (int k0 = 0; k0 < D_DIM; k0 += 16) {
      float4 av  = *(const float4*)(emb + (size_t)(m0 + at) * D_DIM + (k0 + ac));
      float4 bv0 = *(const float4*)(W1 + (size_t)(k0 + br) * H_DIM + (n0 + bc));
      float4 bv1 = *(const float4*)(W1 + (size_t)(k0 + br) * H_DIM + (n0 + bc) + 4);
      __syncthreads();
      As[ac + 0][at] = av.x; As[ac + 1][at] = av.y;
      As[ac + 2][at] = av.z; As[ac + 3][at] = av.w;
      *(float4*)&Bs[br][bc]     = bv0;
      *(float4*)&Bs[br][bc + 4] = bv1;
      __syncthreads();
      #pragma unroll
      for (int k = 0; k < 16; k++) {
        float4 a   = *(const float4*)&As[k][ty << 2];
        float4 b0  = *(const float4*)&Bs[k][tx << 3];
        float4 b1v = *(const float4*)&Bs[k][(tx << 3) + 4];
        float aa[4] = {a.x, a.y, a.z, a.w};
        float bb[8] = {b0.x, b0.y, b0.z, b0.w, b1v.x, b1v.y, b1v.z, b1v.w};
        #pragma unroll
        for (int i = 0; i < 4; i++)
          #pragma unroll
          for (int j = 0; j < 8; j++)
            acc[i][j] = fmaf(aa[i], bb[j], acc[i][j]);
      }
    }
    // epilogue for this H tile: relu + dot with W2
    float4 c0 = *(const float4*)(b1 + n0 + (tx << 3));
    float4 c1 = *(const float4*)(b1 + n0 + (tx << 3) + 4);
    float4 w0 = *(const float4*)(W2 + n0 + (tx << 3));
    float4 w1 = *(const float4*)(W2 + n0 + (tx << 3) + 4);
    float cb[8] = {c0.x, c0.y, c0.z, c0.w, c1.x, c1.y, c1.z, c1.w};
    float wb[8] = {w0.x, w0.y, w0.z, w0.w, w1.x, w1.y, w1.z, w1.w};
    #pragma unroll
    for (int i = 0; i < 4; i++)
      #pragma unroll
      for (int j = 0; j < 8; j++) {
        float h = fmaxf(acc[i][j] + cb[j], 0.f);
        logit[i] = fmaf(h, wb[j], logit[i]);
      }
  }

  __syncthreads();
  #pragma unroll
  for (int i = 0; i < 4; i++) red[(ty << 2) + i][tx] = logit[i];
  __syncthreads();

  if (tid < 64) {
    float s = 0.f;
    #pragma unroll
    for (int x = 0; x < 16; x++) s += red[tid][x];
    s += b2[0];
    int t = m0 + tid;
    uint32_t r1a, r1b, r2a, r2b;
    jax_subkeys(r1a, r1b, r2a, r2b);
    pert[t] = s + gumbel_from_bits(jax_bits32(r2a, r2b, (uint32_t)t));
  }
}

// ---------------- K3: per-row top-k_selected -> hard mask (in place) ----------------
// One block per row. Each block redundantly computes k_selected (deterministic).
// Key packs (ordered float << 12) | index: ties broken toward larger index, which
// matches stable-argsort rank semantics (later index among equals ranks higher).

__global__ __launch_bounds__(256) void topk_kernel(const float* __restrict__ kl,
                                                   float* __restrict__ mask) {
  const int r = blockIdx.x;
  const int tid = threadIdx.x;
  __shared__ int ksel_sh;
  __shared__ unsigned long long wmax[4];

  if (tid < 64) {  // wave 0 computes argmax(k_soft)+1 == argmax(perturbed k-logits)+1
    float p = k_perturbed(tid, kl);
    unsigned long long key =
        ((unsigned long long)ordf(p) << 32) | (unsigned)(63 - tid);  // first-index ties
    #pragma unroll
    for (int off = 32; off >= 1; off >>= 1) {
      unsigned long long o = shflx64(key, off);
      if (o > key) key = o;
    }
    if (tid == 0) ksel_sh = 64 - (int)(key & 0xffffffffu);  // (63 - low) + 1
  }
  __syncthreads();
  const int k = ksel_sh;

  unsigned long long keys[16], okeys[16];
  #pragma unroll
  for (int j = 0; j < 16; j++) {
    int s = tid + (j << 8);
    float v = mask[(r << 12) + s];
    okeys[j] = ((unsigned long long)ordf(v) << 12) | (unsigned)s;
    keys[j] = okeys[j];
  }

  unsigned long long thresh = 0ull;
  for (int it = 0; it < k; it++) {
    unsigned long long lm = 0ull;
    int ls = -1;
    #pragma unroll
    for (int j = 0; j < 16; j++)
      if (keys[j] > lm) { lm = keys[j]; ls = j; }
    unsigned long long wm = lm;
    #pragma unroll
    for (int off = 32; off >= 1; off >>= 1) {
      unsigned long long o = shflx64(wm, off);
      if (o > wm) wm = o;
    }
    __syncthreads();
    if ((tid & 63) == 0) wmax[tid >> 6] = wm;
    __syncthreads();
    unsigned long long gm = wmax[0];
    if (wmax[1] > gm) gm = wmax[1];
    if (wmax[2] > gm) gm = wmax[2];
    if (wmax[3] > gm) gm = wmax[3];
    if (ls >= 0 && keys[ls] == gm) keys[ls] = 0ull;  // keys unique -> only owner removes
    thresh = gm;
  }

  #pragma unroll
  for (int j = 0; j < 16; j++) {
    int s = tid + (j << 8);
    mask[(r << 12) + s] = (okeys[j] >= thresh) ? 1.0f : 0.0f;
  }
}

// ---------------- K4: filtered = emb * mask ----------------

__global__ __launch_bounds__(256) void filter_kernel(const float* __restrict__ emb,
                                                     const float* __restrict__ mask,
                                                     float* __restrict__ out) {
  const int t = blockIdx.x;  // token
  const float mk = mask[t];
  const size_t base = (size_t)t * D_DIM + ((size_t)threadIdx.x << 2);
  float4 v = *(const float4*)(emb + base);
  *(float4*)(out + base) = make_float4(v.x * mk, v.y * mk, v.z * mk, v.w * mk);
}

// ---------------- launcher ----------------

extern "C" void kernel_launch(void* const* d_in, const int* in_sizes, int n_in,
                              void* d_out, int out_size, void* d_ws, size_t ws_size,
                              hipStream_t stream) {
  const float* emb = (const float*)d_in[0];
  const float* W1  = (const float*)d_in[1];
  const float* b1  = (const float*)d_in[2];
  const float* W2  = (const float*)d_in[3];
  const float* b2  = (const float*)d_in[4];
  const float* kl  = (const float*)d_in[5];
  float* out  = (float*)d_out;
  float* mask = out + (size_t)M_TOK * D_DIM;   // [B*S] region of d_out, used as
                                               // perturbed-logit scratch then mask
  float* expk = mask + M_TOK;                  // last element

  kexp_kernel<<<1, 64, 0, stream>>>(kl, expk);
  scorer_kernel<<<M_TOK / 64, 256, 0, stream>>>(emb, W1, b1, W2, b2, mask);
  topk_kernel<<<B_BATCH, 256, 0, stream>>>(kl, mask);
  filter_kernel<<<M_TOK, 256, 0, stream>>>(emb, mask, out);
}

// Round 2
// 726.881 us; speedup vs baseline: 2.8177x; 2.8177x over previous
//
#include <hip/hip_runtime.h>
#include <stdint.h>

#define B_BATCH 8
#define S_SEQ   4096
#define D_DIM   1024
#define H_DIM   2048
#define M_TOK   (B_BATCH * S_SEQ)   // 32768
#define MAXK    64

typedef unsigned int u32;
typedef unsigned short u16;
typedef __attribute__((ext_vector_type(8))) short short8;   // 8 bf16 (4 VGPRs)
typedef __attribute__((ext_vector_type(4))) float f32x4;

#define GLOBAL_AS __attribute__((address_space(1)))
#define LDS_AS    __attribute__((address_space(3)))

// ---------------- JAX threefry2x32 (20 rounds), partitionable mode ----------------

#define TF_ROUND(x0, x1, r) { x0 += x1; x1 = ((x1 << r) | (x1 >> (32 - r))); x1 ^= x0; }

__device__ __forceinline__ void tf2x32(u32 k0, u32 k1, u32 x0, u32 x1, u32& o0, u32& o1) {
  u32 k2 = k0 ^ k1 ^ 0x1BD11BDAu;
  x0 += k0; x1 += k1;
  TF_ROUND(x0, x1, 13) TF_ROUND(x0, x1, 15) TF_ROUND(x0, x1, 26) TF_ROUND(x0, x1, 6)
  x0 += k1; x1 += k2 + 1u;
  TF_ROUND(x0, x1, 17) TF_ROUND(x0, x1, 29) TF_ROUND(x0, x1, 16) TF_ROUND(x0, x1, 24)
  x0 += k2; x1 += k0 + 2u;
  TF_ROUND(x0, x1, 13) TF_ROUND(x0, x1, 15) TF_ROUND(x0, x1, 26) TF_ROUND(x0, x1, 6)
  x0 += k0; x1 += k1 + 3u;
  TF_ROUND(x0, x1, 17) TF_ROUND(x0, x1, 29) TF_ROUND(x0, x1, 16) TF_ROUND(x0, x1, 24)
  x0 += k1; x1 += k2 + 4u;
  TF_ROUND(x0, x1, 13) TF_ROUND(x0, x1, 15) TF_ROUND(x0, x1, 26) TF_ROUND(x0, x1, 6)
  x0 += k2; x1 += k0 + 5u;
  o0 = x0; o1 = x1;
}

__device__ __forceinline__ void jax_subkeys(u32& r1a, u32& r1b, u32& r2a, u32& r2b) {
  tf2x32(0u, 42u, 0u, 0u, r1a, r1b);
  tf2x32(0u, 42u, 0u, 1u, r2a, r2b);
}

__device__ __forceinline__ u32 jax_bits32(u32 ka, u32 kb, u32 i) {
  u32 o0, o1;
  tf2x32(ka, kb, 0u, i, o0, o1);
  return o0 ^ o1;
}

__device__ __forceinline__ float jax_uniform_from_bits(u32 bits) {
  float f = __uint_as_float((bits >> 9) | 0x3f800000u) - 1.0f;
  float r = f + 1e-8f;
  return fmaxf(1e-8f, r);
}

__device__ __forceinline__ float gumbel_from_bits(u32 bits) {
  float u = jax_uniform_from_bits(bits);
  return -logf(-logf(u));
}

__device__ __forceinline__ float k_perturbed(int i, const float* kl) {
  u32 r1a, r1b, r2a, r2b;
  jax_subkeys(r1a, r1b, r2a, r2b);
  return kl[i] + gumbel_from_bits(jax_bits32(r1a, r1b, (u32)i));
}

__device__ __forceinline__ u32 ordf(float v) {
  u32 b = __float_as_uint(v);
  return (b & 0x80000000u) ? ~b : (b | 0x80000000u);
}

__device__ __forceinline__ unsigned long long shflx64(unsigned long long v, int m) {
  unsigned lo = (unsigned)v, hi = (unsigned)(v >> 32);
  lo = (unsigned)__shfl_xor((int)lo, m);
  hi = (unsigned)__shfl_xor((int)hi, m);
  return ((unsigned long long)hi << 32) | lo;
}

// ---------------- bf16 split helpers ----------------

__device__ __forceinline__ u16 f2bf_rn(float x) {
  u32 u = __float_as_uint(x);
  u32 r = u + 0x7fffu + ((u >> 16) & 1u);
  return (u16)(r >> 16);
}

__device__ __forceinline__ void split1(float x, u16& h, u16& lo) {
  h = f2bf_rn(x);
  float hf = __uint_as_float(((u32)h) << 16);
  lo = f2bf_rn(x - hf);
}

// ---------------- K1: expected_k (single wave) ----------------

__global__ void kexp_kernel(const float* __restrict__ kl, float* __restrict__ expk) {
  int i = threadIdx.x;
  float p = k_perturbed(i, kl);
  float m = p;
  #pragma unroll
  for (int off = 32; off >= 1; off >>= 1) m = fmaxf(m, __shfl_xor(m, off));
  float e = expf(p - m);
  float s = e;
  #pragma unroll
  for (int off = 32; off >= 1; off >>= 1) s += __shfl_xor(s, off);
  float v = (e / s) * (float)(i + 1);
  #pragma unroll
  for (int off = 32; off >= 1; off >>= 1) v += __shfl_xor(v, off);
  if (i == 0) expk[0] = v;
}

// ---------------- split pre-passes ----------------

__global__ __launch_bounds__(256) void split_a_kernel(const float* __restrict__ x,
                                                      u16* __restrict__ hi,
                                                      u16* __restrict__ lo) {
  const size_t i = ((size_t)blockIdx.x * 256 + threadIdx.x) * 4;
  float4 v = *(const float4*)(x + i);
  u16 h0, h1, h2, h3, l0, l1, l2, l3;
  split1(v.x, h0, l0); split1(v.y, h1, l1); split1(v.z, h2, l2); split1(v.w, h3, l3);
  unsigned long long hv = (unsigned long long)h0 | ((unsigned long long)h1 << 16) |
                          ((unsigned long long)h2 << 32) | ((unsigned long long)h3 << 48);
  unsigned long long lv = (unsigned long long)l0 | ((unsigned long long)l1 << 16) |
                          ((unsigned long long)l2 << 32) | ((unsigned long long)l3 << 48);
  *(unsigned long long*)(hi + i) = hv;
  *(unsigned long long*)(lo + i) = lv;
}

// transpose W1 [D][H] -> W1t [H][D], split to hi/lo bf16
__global__ __launch_bounds__(256) void split_w1t_kernel(const float* __restrict__ W1,
                                                        u16* __restrict__ bhi,
                                                        u16* __restrict__ blo) {
  __shared__ float tile[32][33];
  const int tx = threadIdx.x & 31, ty = threadIdx.x >> 5;  // ty 0..7
  const int n0 = blockIdx.x * 32, k0 = blockIdx.y * 32;
  #pragma unroll
  for (int r = 0; r < 4; ++r)
    tile[ty + r * 8][tx] = W1[(size_t)(k0 + ty + r * 8) * H_DIM + n0 + tx];
  __syncthreads();
  #pragma unroll
  for (int r = 0; r < 4; ++r) {
    const int n = n0 + ty + r * 8, k = k0 + tx;
    u16 h, l;
    split1(tile[tx][ty + r * 8], h, l);
    bhi[(size_t)n * D_DIM + k] = h;
    blo[(size_t)n * D_DIM + k] = l;
  }
}

// ---------------- K2: bf16x3 MFMA fused scorer ----------------
// grid (256, 2): x = 128-token tile, y = H half (1024 each, 8 x 128 tiles).
// 256 threads = 4 waves in 2x2; wave tile 64x64; 16x16x32 bf16 MFMA.
// LDS tiles [row][BK=32] with XOR chunk swizzle slot = kc ^ ((row>>1)&3).

__device__ __forceinline__ void stage16(const u16* g, u16* l) {
  __builtin_amdgcn_global_load_lds((const GLOBAL_AS u32*)g, (LDS_AS u32*)l, 16, 0, 0);
}

__global__ __launch_bounds__(256, 2) void scorer_mfma(
    const u16* __restrict__ Ahi, const u16* __restrict__ Alo,
    const u16* __restrict__ Bhi, const u16* __restrict__ Blo,
    const float* __restrict__ b1, const float* __restrict__ W2,
    float* __restrict__ pl) {
  __shared__ u16 smem[4 * 128 * 32];  // 32 KB: Ahi | Alo | Bhi | Blo tiles
  u16* sAhi = smem;
  u16* sAlo = smem + 4096;
  u16* sBhi = smem + 8192;
  u16* sBlo = smem + 12288;

  const int tid = threadIdx.x;
  const int w = tid >> 6;   // wave 0..3
  const int l = tid & 63;
  const int m0 = blockIdx.x * 128;
  const int nyb = blockIdx.y;

  // staging geometry (per lane, per t in {0,1}): 16 rows per instr, slot = l&3
  const int rl0 = w * 32 + (l >> 2);       // t=0 row_local; t=1 adds 16
  const int rl1 = rl0 + 16;
  const int kloc0 = (((l & 3) ^ ((rl0 >> 1) & 3)) << 3);  // swizzled k offset (elems)
  const int kloc1 = (((l & 3) ^ ((rl1 >> 1) & 3)) << 3);
  const int lb0 = (w * 32) * 32;           // LDS elem base for t=0
  const int lb1 = (w * 32 + 16) * 32;

  // frag read offsets (elements), fixed for whole kernel
  int a_off[4], b_off[4];
  #pragma unroll
  for (int i = 0; i < 4; ++i) {
    int row = ((w & 1) << 6) + i * 16 + (l & 15);
    int slot = (l >> 4) ^ ((row >> 1) & 3);
    a_off[i] = row * 32 + slot * 8;
    int nrow = ((w >> 1) << 6) + i * 16 + (l & 15);
    int nslot = (l >> 4) ^ ((nrow >> 1) & 3);
    b_off[i] = nrow * 32 + nslot * 8;
  }

  float logit[4][4];
  #pragma unroll
  for (int i = 0; i < 4; ++i)
    #pragma unroll
    for (int r = 0; r < 4; ++r) logit[i][r] = 0.f;

  for (int t8 = 0; t8 < 8; ++t8) {
    const int n0 = nyb * 1024 + t8 * 128;
    f32x4 acc[4][4];
    #pragma unroll
    for (int i = 0; i < 4; ++i)
      #pragma unroll
      for (int j = 0; j < 4; ++j) acc[i][j] = (f32x4){0.f, 0.f, 0.f, 0.f};

    const u16* pA0h = Ahi + (size_t)(m0 + rl0) * D_DIM + kloc0;
    const u16* pA1h = Ahi + (size_t)(m0 + rl1) * D_DIM + kloc1;
    const u16* pA0l = Alo + (size_t)(m0 + rl0) * D_DIM + kloc0;
    const u16* pA1l = Alo + (size_t)(m0 + rl1) * D_DIM + kloc1;
    const u16* pB0h = Bhi + (size_t)(n0 + rl0) * D_DIM + kloc0;
    const u16* pB1h = Bhi + (size_t)(n0 + rl1) * D_DIM + kloc1;
    const u16* pB0l = Blo + (size_t)(n0 + rl0) * D_DIM + kloc0;
    const u16* pB1l = Blo + (size_t)(n0 + rl1) * D_DIM + kloc1;

    for (int k0 = 0; k0 < D_DIM; k0 += 32) {
      __syncthreads();  // previous stage fully consumed
      stage16(pA0h, sAhi + lb0); stage16(pA1h, sAhi + lb1);
      stage16(pA0l, sAlo + lb0); stage16(pA1l, sAlo + lb1);
      stage16(pB0h, sBhi + lb0); stage16(pB1h, sBhi + lb1);
      stage16(pB0l, sBlo + lb0); stage16(pB1l, sBlo + lb1);
      pA0h += 32; pA1h += 32; pA0l += 32; pA1l += 32;
      pB0h += 32; pB1h += 32; pB0l += 32; pB1l += 32;
      __syncthreads();  // loads landed (vmcnt drained before barrier)

      short8 ah[4], al[4], bh[4], bl[4];
      #pragma unroll
      for (int i = 0; i < 4; ++i) {
        ah[i] = *(const short8*)(sAhi + a_off[i]);
        al[i] = *(const short8*)(sAlo + a_off[i]);
        bh[i] = *(const short8*)(sBhi + b_off[i]);
        bl[i] = *(const short8*)(sBlo + b_off[i]);
      }
      #pragma unroll
      for (int i = 0; i < 4; ++i)
        #pragma unroll
        for (int j = 0; j < 4; ++j) {
          acc[i][j] = __builtin_amdgcn_mfma_f32_16x16x32_bf16(ah[i], bh[j], acc[i][j], 0, 0, 0);
          acc[i][j] = __builtin_amdgcn_mfma_f32_16x16x32_bf16(ah[i], bl[j], acc[i][j], 0, 0, 0);
          acc[i][j] = __builtin_amdgcn_mfma_f32_16x16x32_bf16(al[i], bh[j], acc[i][j], 0, 0, 0);
        }
    }

    // epilogue: relu(acc + b1) dot W2, accumulate per-m partial
    const int nb = n0 + ((w >> 1) << 6);
    #pragma unroll
    for (int j = 0; j < 4; ++j) {
      const int n = nb + j * 16 + (l & 15);
      const float b1v = b1[n];
      const float w2v = W2[n];
      #pragma unroll
      for (int i = 0; i < 4; ++i)
        #pragma unroll
        for (int r = 0; r < 4; ++r)
          logit[i][r] += fmaxf(acc[i][j][r] + b1v, 0.f) * w2v;
    }
  }

  // cross-lane/wave reduction: red[128][33] aliases stage memory
  __syncthreads();
  float* red = (float*)smem;
  const int col = (l & 15) + ((w >> 1) << 4);
  #pragma unroll
  for (int i = 0; i < 4; ++i)
    #pragma unroll
    for (int r = 0; r < 4; ++r) {
      const int m = ((w & 1) << 6) + i * 16 + ((l >> 4) << 2) + r;
      red[m * 33 + col] = logit[i][r];
    }
  __syncthreads();
  if (tid < 128) {
    float s = 0.f;
    #pragma unroll
    for (int x = 0; x < 32; ++x) s += red[tid * 33 + x];
    pl[(size_t)nyb * M_TOK + m0 + tid] = s;
  }
}

// ---------------- fallback fp32 scorer (used only if ws too small) ----------------

__global__ __launch_bounds__(256) void scorer_kernel(
    const float* __restrict__ emb, const float* __restrict__ W1,
    const float* __restrict__ b1, const float* __restrict__ W2,
    const float* __restrict__ b2, float* __restrict__ pert) {
  __shared__ float As[16][68];
  __shared__ float Bs[16][132];
  __shared__ float red[64][17];

  const int tid = threadIdx.x;
  const int tx = tid & 15;
  const int ty = tid >> 4;
  const int m0 = blockIdx.x * 64;
  const int at = tid >> 2;
  const int ac = (tid & 3) << 2;
  const int br = tid >> 4;
  const int bc = (tid & 15) << 3;

  float logit[4] = {0.f, 0.f, 0.f, 0.f};

  for (int n0 = 0; n0 < H_DIM; n0 += 128) {
    float acc[4][8];
    #pragma unroll
    for (int i = 0; i < 4; i++)
      #pragma unroll
      for (int j = 0; j < 8; j++) acc[i][j] = 0.f;

    for (int k0 = 0; k0 < D_DIM; k0 += 16) {
      float4 av  = *(const float4*)(emb + (size_t)(m0 + at) * D_DIM + (k0 + ac));
      float4 bv0 = *(const float4*)(W1 + (size_t)(k0 + br) * H_DIM + (n0 + bc));
      float4 bv1 = *(const float4*)(W1 + (size_t)(k0 + br) * H_DIM + (n0 + bc) + 4);
      __syncthreads();
      As[ac + 0][at] = av.x; As[ac + 1][at] = av.y;
      As[ac + 2][at] = av.z; As[ac + 3][at] = av.w;
      *(float4*)&Bs[br][bc]     = bv0;
      *(float4*)&Bs[br][bc + 4] = bv1;
      __syncthreads();
      #pragma unroll
      for (int k = 0; k < 16; k++) {
        float4 a   = *(const float4*)&As[k][ty << 2];
        float4 b0  = *(const float4*)&Bs[k][tx << 3];
        float4 b1v = *(const float4*)&Bs[k][(tx << 3) + 4];
        float aa[4] = {a.x, a.y, a.z, a.w};
        float bb[8] = {b0.x, b0.y, b0.z, b0.w, b1v.x, b1v.y, b1v.z, b1v.w};
        #pragma unroll
        for (int i = 0; i < 4; i++)
          #pragma unroll
          for (int j = 0; j < 8; j++)
            acc[i][j] = fmaf(aa[i], bb[j], acc[i][j]);
      }
    }
    float4 c0 = *(const float4*)(b1 + n0 + (tx << 3));
    float4 c1 = *(const float4*)(b1 + n0 + (tx << 3) + 4);
    float4 w0 = *(const float4*)(W2 + n0 + (tx << 3));
    float4 w1 = *(const float4*)(W2 + n0 + (tx << 3) + 4);
    float cb[8] = {c0.x, c0.y, c0.z, c0.w, c1.x, c1.y, c1.z, c1.w};
    float wb[8] = {w0.x, w0.y, w0.z, w0.w, w1.x, w1.y, w1.z, w1.w};
    #pragma unroll
    for (int i = 0; i < 4; i++)
      #pragma unroll
      for (int j = 0; j < 8; j++) {
        float h = fmaxf(acc[i][j] + cb[j], 0.f);
        logit[i] = fmaf(h, wb[j], logit[i]);
      }
  }

  __syncthreads();
  #pragma unroll
  for (int i = 0; i < 4; i++) red[(ty << 2) + i][tx] = logit[i];
  __syncthreads();

  if (tid < 64) {
    float s = 0.f;
    #pragma unroll
    for (int x = 0; x < 16; x++) s += red[tid][x];
    s += b2[0];
    int t = m0 + tid;
    u32 r1a, r1b, r2a, r2b;
    jax_subkeys(r1a, r1b, r2a, r2b);
    pert[t] = s + gumbel_from_bits(jax_bits32(r2a, r2b, (u32)t));
  }
}

// ---------------- K3: per-row top-k -> hard mask ----------------
// variant A (main path): perturbed computed from partial logits pl[0/1] + b2 + gumbel
// variant B (fallback): perturbed pre-written in mask region

template <bool FROM_PL>
__device__ __forceinline__ void topk_body(const float* kl, const float* pl,
                                          const float* b2, float* mask) {
  const int r = blockIdx.x;
  const int tid = threadIdx.x;
  __shared__ int ksel_sh;
  __shared__ unsigned long long wmax[4];

  u32 r1a, r1b, r2a, r2b;
  jax_subkeys(r1a, r1b, r2a, r2b);

  if (tid < 64) {
    float p = kl[tid] + gumbel_from_bits(jax_bits32(r1a, r1b, (u32)tid));
    unsigned long long key =
        ((unsigned long long)ordf(p) << 32) | (unsigned)(63 - tid);
    #pragma unroll
    for (int off = 32; off >= 1; off >>= 1) {
      unsigned long long o = shflx64(key, off);
      if (o > key) key = o;
    }
    if (tid == 0) ksel_sh = 64 - (int)(key & 0xffffffffu);
  }
  __syncthreads();
  const int k = ksel_sh;
  const float b2v = FROM_PL ? b2[0] : 0.f;

  unsigned long long keys[16], okeys[16];
  #pragma unroll
  for (int j = 0; j < 16; j++) {
    int s = tid + (j << 8);
    int t = (r << 12) + s;
    float v;
    if (FROM_PL) {
      v = pl[t] + pl[M_TOK + t] + b2v + gumbel_from_bits(jax_bits32(r2a, r2b, (u32)t));
    } else {
      v = mask[t];
    }
    okeys[j] = ((unsigned long long)ordf(v) << 12) | (unsigned)s;
    keys[j] = okeys[j];
  }

  unsigned long long thresh = 0ull;
  for (int it = 0; it < k; it++) {
    unsigned long long lm = 0ull;
    int ls = -1;
    #pragma unroll
    for (int j = 0; j < 16; j++)
      if (keys[j] > lm) { lm = keys[j]; ls = j; }
    unsigned long long wm = lm;
    #pragma unroll
    for (int off = 32; off >= 1; off >>= 1) {
      unsigned long long o = shflx64(wm, off);
      if (o > wm) wm = o;
    }
    __syncthreads();
    if ((tid & 63) == 0) wmax[tid >> 6] = wm;
    __syncthreads();
    unsigned long long gm = wmax[0];
    if (wmax[1] > gm) gm = wmax[1];
    if (wmax[2] > gm) gm = wmax[2];
    if (wmax[3] > gm) gm = wmax[3];
    if (ls >= 0 && keys[ls] == gm) keys[ls] = 0ull;
    thresh = gm;
  }

  #pragma unroll
  for (int j = 0; j < 16; j++) {
    int s = tid + (j << 8);
    mask[(r << 12) + s] = (okeys[j] >= thresh) ? 1.0f : 0.0f;
  }
}

__global__ __launch_bounds__(256) void topk_pl_kernel(const float* __restrict__ kl,
                                                      const float* __restrict__ pl,
                                                      const float* __restrict__ b2,
                                                      float* __restrict__ mask) {
  topk_body<true>(kl, pl, b2, mask);
}

__global__ __launch_bounds__(256) void topk_kernel(const float* __restrict__ kl,
                                                   float* __restrict__ mask) {
  topk_body<false>(kl, nullptr, nullptr, mask);
}

// ---------------- K4: filtered = emb * mask ----------------

__global__ __launch_bounds__(256) void filter_kernel(const float* __restrict__ emb,
                                                     const float* __restrict__ mask,
                                                     float* __restrict__ out) {
  const int t = blockIdx.x;
  const float mk = mask[t];
  const size_t base = (size_t)t * D_DIM + ((size_t)threadIdx.x << 2);
  float4 v = *(const float4*)(emb + base);
  *(float4*)(out + base) = make_float4(v.x * mk, v.y * mk, v.z * mk, v.w * mk);
}

// ---------------- launcher ----------------

extern "C" void kernel_launch(void* const* d_in, const int* in_sizes, int n_in,
                              void* d_out, int out_size, void* d_ws, size_t ws_size,
                              hipStream_t stream) {
  const float* emb = (const float*)d_in[0];
  const float* W1  = (const float*)d_in[1];
  const float* b1  = (const float*)d_in[2];
  const float* W2  = (const float*)d_in[3];
  const float* b2  = (const float*)d_in[4];
  const float* kl  = (const float*)d_in[5];
  float* out  = (float*)d_out;
  float* mask = out + (size_t)M_TOK * D_DIM;
  float* expk = mask + M_TOK;

  const size_t ws_need = (size_t)H_DIM * D_DIM * 2 * 2 + (size_t)2 * M_TOK * 4;

  kexp_kernel<<<1, 64, 0, stream>>>(kl, expk);

  if (ws_size >= ws_need) {
    // A split lives in the d_out embeddings region (exactly M*D*4 bytes)
    u16* Ahi = (u16*)d_out;
    u16* Alo = Ahi + (size_t)M_TOK * D_DIM;
    u16* Bhi = (u16*)d_ws;
    u16* Blo = Bhi + (size_t)H_DIM * D_DIM;
    float* pl = (float*)(Blo + (size_t)H_DIM * D_DIM);

    split_a_kernel<<<M_TOK * D_DIM / 1024, 256, 0, stream>>>(emb, Ahi, Alo);
    split_w1t_kernel<<<dim3(H_DIM / 32, D_DIM / 32), 256, 0, stream>>>(W1, Bhi, Blo);
    scorer_mfma<<<dim3(M_TOK / 128, 2), 256, 0, stream>>>(Ahi, Alo, Bhi, Blo, b1, W2, pl);
    topk_pl_kernel<<<B_BATCH, 256, 0, stream>>>(kl, pl, b2, mask);
  } else {
    scorer_kernel<<<M_TOK / 64, 256, 0, stream>>>(emb, W1, b1, W2, b2, mask);
    topk_kernel<<<B_BATCH, 256, 0, stream>>>(kl, mask);
  }

  filter_kernel<<<M_TOK, 256, 0, stream>>>(emb, mask, out);
}